// Round 8
// baseline (336.372 us; speedup 1.0000x reference)
//
#include <hip/hip_runtime.h>
#include <hip/hip_bf16.h>

// Problem constants
#define B_SZ 8192
#define D_SZ 512
#define K_SZ 4096
#define L_SZ 16
#define M_ALL (B_SZ + K_SZ)   // 12288 rows: targets stacked over codebook

typedef __attribute__((ext_vector_type(8))) short short8v;      // 8 bf16
typedef __attribute__((ext_vector_type(4))) float f32x4;
typedef _Float16 half8v __attribute__((ext_vector_type(8)));    // 8 fp16 = 16B
typedef _Float16 h2 __attribute__((ext_vector_type(2)));        // packed fp16 pair
struct H2x4 { h2 a, b, c, d; };                                 // = one half8v

typedef const __attribute__((address_space(1))) void gvoid;
typedef __attribute__((address_space(3))) void lvoid;

static __device__ __forceinline__ h2 habs2(h2 a) {
    unsigned u = __builtin_bit_cast(unsigned, a) & 0x7FFF7FFFu;
    return __builtin_bit_cast(h2, u);
}
static __device__ __forceinline__ h2 hmax2(h2 a, h2 b) {
#if __has_builtin(__builtin_elementwise_max)
    return __builtin_elementwise_max(a, b);
#else
    h2 r; r[0] = a[0] > b[0] ? a[0] : b[0]; r[1] = a[1] > b[1] ? a[1] : b[1]; return r;
#endif
}

// ---------------------------------------------------------------------------
// Kernel 1: cast targets+codebook (fp32) into one stacked bf16 matrix [12288 x 512]
// ---------------------------------------------------------------------------
__global__ void cast_bf16_kernel(const float* __restrict__ targets,
                                 const float* __restrict__ codebook,
                                 __hip_bfloat16* __restrict__ abf) {
    int idx = blockIdx.x * blockDim.x + threadIdx.x;
    const int total4 = (M_ALL * D_SZ) / 4;
    if (idx >= total4) return;
    int base = idx * 4;
    const float* src = (base < B_SZ * D_SZ) ? (targets + base)
                                            : (codebook + (base - B_SZ * D_SZ));
    float4 v = *(const float4*)src;
    abf[base + 0] = __float2bfloat16(v.x);
    abf[base + 1] = __float2bfloat16(v.y);
    abf[base + 2] = __float2bfloat16(v.z);
    abf[base + 3] = __float2bfloat16(v.w);
}

// ---------------------------------------------------------------------------
// Kernel 1b: exact fp64 codebook row norms^2 (for algebraic ||r||^2 update)
// ---------------------------------------------------------------------------
__global__ void cn2_kernel(const float* __restrict__ codebook,
                           double* __restrict__ cn2) {
    int row  = blockIdx.x * 4 + (threadIdx.x >> 6);
    int lane = threadIdx.x & 63;
    const float* r = codebook + (size_t)row * D_SZ;
    double s = 0.0;
#pragma unroll
    for (int j = 0; j < 8; j++) { double v = (double)r[lane + 64 * j]; s += v * v; }
#pragma unroll
    for (int o = 32; o > 0; o >>= 1) s += __shfl_down(s, o, 64);
    if (lane == 0) cn2[row] = s;
}

// ---------------------------------------------------------------------------
// Kernel 2: S = A * B^T -> fp16 [M x 4096]. 128x128 tile, 4 waves, 16x16x32
// MFMA. global_load_lds width=16 staging (m97 pattern), unpadded [128][32].
// ---------------------------------------------------------------------------
#define BM 128
#define BN 128
#define BK 32   // bf16 elems: 64 B per LDS row, unpadded

__global__ __launch_bounds__(256)
void gemm_bt_kernel(const __hip_bfloat16* __restrict__ A,
                    const __hip_bfloat16* __restrict__ Bm,
                    _Float16* __restrict__ C) {
    __shared__ short As[BM * BK];   // 8 KB
    __shared__ short Bs[BN * BK];   // 8 KB
    const int tid  = threadIdx.x;
    const int bm   = blockIdx.y * BM;
    const int bn   = blockIdx.x * BN;
    const int wave = tid >> 6, lane = tid & 63;
    const int wm = (wave & 1) * 64, wn = (wave >> 1) * 64;
    const int row16 = lane & 15, quad = lane >> 4;
    const int koff = quad * 8;

    f32x4 acc[4][4] = {};

    const short* Ag = (const short*)A;
    const short* Bg = (const short*)Bm;
    const int srow = lane >> 2;          // 0..15 within a 16-row group
    const int scol = (lane & 3) * 8;     // elem offset 0/8/16/24 (16 B chunks)

    for (int k0 = 0; k0 < D_SZ; k0 += BK) {
        __syncthreads();   // protect previous iteration's fragment reads
#pragma unroll
        for (int c = 0; c < 2; c++) {
            int row = (wave * 2 + c) * 16 + srow;
            __builtin_amdgcn_global_load_lds(
                (gvoid*)(Ag + (size_t)(bm + row) * D_SZ + k0 + scol),
                (lvoid*)(As + row * BK + scol), 16, 0, 0);
            __builtin_amdgcn_global_load_lds(
                (gvoid*)(Bg + (size_t)(bn + row) * D_SZ + k0 + scol),
                (lvoid*)(Bs + row * BK + scol), 16, 0, 0);
        }
        __syncthreads();   // drains vmcnt -> LDS tiles complete

        short8v af[4], bf[4];
#pragma unroll
        for (int i = 0; i < 4; i++)
            af[i] = *(const short8v*)(As + (wm + i * 16 + row16) * BK + koff);
#pragma unroll
        for (int j = 0; j < 4; j++)
            bf[j] = *(const short8v*)(Bs + (wn + j * 16 + row16) * BK + koff);
#pragma unroll
        for (int i = 0; i < 4; i++)
#pragma unroll
            for (int j = 0; j < 4; j++)
                acc[i][j] = __builtin_amdgcn_mfma_f32_16x16x32_bf16(af[i], bf[j], acc[i][j], 0, 0, 0);
    }

    // C/D layout: col = lane&15, row = quad*4 + reg  [m89/m91 verified]
    if (bm < B_SZ) {
        // score region: written once, read once by pursuit -> non-temporal
#pragma unroll
        for (int i = 0; i < 4; i++) {
            int grow = bm + wm + i * 16 + quad * 4;
#pragma unroll
            for (int j = 0; j < 4; j++) {
                int gcol = bn + wn + j * 16 + row16;
#pragma unroll
                for (int r = 0; r < 4; r++)
                    __builtin_nontemporal_store((_Float16)acc[i][j][r],
                                                &C[(size_t)(grow + r) * K_SZ + gcol]);
            }
        }
    } else {
        // Gram region: hot random-access data for pursuit -> keep cached
#pragma unroll
        for (int i = 0; i < 4; i++) {
            int grow = bm + wm + i * 16 + quad * 4;
#pragma unroll
            for (int j = 0; j < 4; j++) {
                int gcol = bn + wn + j * 16 + row16;
#pragma unroll
                for (int r = 0; r < 4; r++)
                    C[(size_t)(grow + r) * K_SZ + gcol] = (_Float16)acc[i][j][r];
            }
        }
    }
}

// ---------------------------------------------------------------------------
// Kernel 3: pursuit, wave-per-row, g in LDS fp16 (8 KB/row, conflict-free
// b128). New in R8: granule-max regs gmf[8] guide the candidate scan
// (~1 granule instead of 8); ballot fast path (no LDS atomics/fence/cnt in
// the 1-candidate case); early sign from fp16 value (provably exact when
// M >= 4: candidate |fp16| >= M-1.5, accumulated err < 1.5 by the margin
// design) lets the g-update interleave with the fp64 dot butterfly; nc>=2
// prefetches the fp16-argmax guess's Gram row during exact rescore.
// ---------------------------------------------------------------------------
#define MAXC 16
#define MARGIN 1.5f

__global__ __launch_bounds__(256, 4)
void pursuit_kernel(const float* __restrict__ targets,
                    const float* __restrict__ codebook,
                    const _Float16* __restrict__ S,   // [12288 x 4096]; rows >=8192 are Gram
                    const double* __restrict__ cn2,   // [4096] exact ||c_k||^2
                    float* __restrict__ out) {
    const int wave = threadIdx.x >> 6;
    const int lane = threadIdx.x & 63;
    const int b = blockIdx.x * 4 + wave;
    const int lane8 = lane * 8;

    __shared__ alignas(16) _Float16 g_s[4][K_SZ];
    __shared__ int   s_cnt[4];
    __shared__ int   s_ci[4][MAXC];
    __shared__ float s_cv[4][MAXC];
    _Float16* g = g_s[wave];
    int* cnt = &s_cnt[wave];
    int* ci  = s_ci[wave];
    float* cv = s_cv[wave];

    float gmf[8];   // per-granule abs-max (granule = 8 contiguous fp16 this lane owns)
    float m;        // lane abs-max

    // ---- init: score row -> LDS (non-temporal), granule maxes in flight ----
    {
        const _Float16* g0 = S + (size_t)b * K_SZ + lane8;
        m = 0.0f;
#pragma unroll
        for (int c = 0; c < 8; c++) {
            half8v h = __builtin_nontemporal_load((const half8v*)(g0 + c * 512));
            *(half8v*)&g[c * 512 + lane8] = h;
            H2x4 u = __builtin_bit_cast(H2x4, h);
            h2 gm2 = hmax2(hmax2(habs2(u.a), habs2(u.b)),
                           hmax2(habs2(u.c), habs2(u.d)));
            gmf[c] = fmaxf((float)gm2[0], (float)gm2[1]);
            m = fmaxf(m, gmf[c]);
        }
    }

    // ---- lane-private fp64 residual + tn2 ----
    double rres[8];
    double loc = 0.0;
    {
        const float* tg = targets + (size_t)b * D_SZ + lane8;
        f32x4 t0 = __builtin_nontemporal_load((const f32x4*)tg);
        f32x4 t1 = __builtin_nontemporal_load((const f32x4*)(tg + 4));
        rres[0] = t0[0]; rres[1] = t0[1]; rres[2] = t0[2]; rres[3] = t0[3];
        rres[4] = t1[0]; rres[5] = t1[1]; rres[6] = t1[2]; rres[7] = t1[3];
#pragma unroll
        for (int e = 0; e < 8; e++) loc += rres[e] * rres[e];
    }
#pragma unroll
    for (int o = 32; o > 0; o >>= 1) loc += __shfl_xor(loc, o, 64);
    double rn2 = loc;
    const bool tgt_ok = (sqrt(loc) >= 1e-8);

    float* out_seq  = out + (size_t)b * L_SZ;
    float* out_mask = out + (size_t)B_SZ * L_SZ + (size_t)b * L_SZ;
    float* out_res  = out + (size_t)2 * B_SZ * L_SZ + (size_t)b * D_SZ;

    // exact fp64 dot of rres with a codebook-row slice pair (butterfly -> all lanes)
    auto edot = [&](const float4& a0, const float4& a1) -> double {
        double s = rres[0] * (double)a0.x + rres[1] * (double)a0.y
                 + rres[2] * (double)a0.z + rres[3] * (double)a0.w
                 + rres[4] * (double)a1.x + rres[5] * (double)a1.y
                 + rres[6] * (double)a1.z + rres[7] * (double)a1.w;
#pragma unroll
        for (int o = 32; o > 0; o >>= 1) s += __shfl_xor(s, o, 64);
        return s;
    };

    // fused g update (LDS RMW) + granule-max + lane-max refresh
    auto upd = [&](const half8v* Gh, h2 sdh2) {
        m = 0.0f;
#pragma unroll
        for (int c = 0; c < 8; c++) {
            half8v gv = *(const half8v*)&g[c * 512 + lane8];
            H2x4 ug = __builtin_bit_cast(H2x4, gv);
            H2x4 uG = __builtin_bit_cast(H2x4, Gh[c]);
            ug.a -= sdh2 * uG.a; ug.b -= sdh2 * uG.b;
            ug.c -= sdh2 * uG.c; ug.d -= sdh2 * uG.d;
            *(half8v*)&g[c * 512 + lane8] = __builtin_bit_cast(half8v, ug);
            h2 gm2 = hmax2(hmax2(habs2(ug.a), habs2(ug.b)),
                           hmax2(habs2(ug.c), habs2(ug.d)));
            gmf[c] = fmaxf((float)gm2[0], (float)gm2[1]);
            m = fmaxf(m, gmf[c]);
        }
    };

    double decay = 1.0;

    for (int t = 0; t < L_SZ; t++) {
        decay *= 0.95;
        bool active = (sqrt(rn2) >= 0.01) && tgt_ok;   // wave-uniform
        if (!active) {                                 // stays inactive forever
            if (lane == 0)
                for (int tt = t; tt < L_SZ; tt++) {
                    __builtin_nontemporal_store(0.0f, &out_seq[tt]);
                    __builtin_nontemporal_store(0.0f, &out_mask[tt]);
                }
            break;
        }

        // ---- wave max + threshold ----
        float M = m;
#pragma unroll
        for (int o = 32; o > 0; o >>= 1) M = fmaxf(M, __shfl_xor(M, o, 64));
        float thr = M - MARGIN;

        // ---- flagged lanes: granule-guided scan (usually 1 granule) ----
        unsigned long long mask = __ballot(m >= thr);
        int npl = __popcll(mask);
        int src = __ffsll((long long)mask) - 1;

        int lcnt = 0, lidx = 0; float lval = 0.0f;
        if (m >= thr) {
#pragma unroll
            for (int c = 0; c < 8; c++)
                if (gmf[c] >= thr) {
                    half8v h = *(const half8v*)&g[c * 512 + lane8];
#pragma unroll
                    for (int e = 0; e < 8; e++) {
                        float f = (float)h[e];
                        if (fabsf(f) >= thr) { lcnt++; lidx = c * 512 + lane8 + e; lval = f; }
                    }
                }
        }

        bool fast = false;
        int bk = 0; float gval = 0.0f; int nc = 1;
        if (npl == 1) {
            int cw = __shfl(lcnt, src, 64);
            if (cw == 1) {
                fast = true;
                bk   = __builtin_amdgcn_readfirstlane(__shfl(lidx, src, 64));
                gval = __shfl(lval, src, 64);
            }
        }
        if (!fast) {
            // ---- slow path (rare): LDS candidate list ----
            if (lane == 0) *cnt = 0;
            __threadfence_block();
            if (lcnt > 0) {
#pragma unroll
                for (int c = 0; c < 8; c++)
                    if (gmf[c] >= thr) {
                        half8v h = *(const half8v*)&g[c * 512 + lane8];
#pragma unroll
                        for (int e = 0; e < 8; e++) {
                            float f = (float)h[e];
                            if (fabsf(f) >= thr) {
                                int q = atomicAdd(cnt, 1);
                                if (q < MAXC) { ci[q] = c * 512 + lane8 + e; cv[q] = f; }
                            }
                        }
                    }
            }
            __threadfence_block();
            nc = min(*cnt, MAXC);
            // guess = fp16-argmax candidate (prefetch target only; not a decision)
            bk = __builtin_amdgcn_readfirstlane(ci[0]); gval = cv[0];
            for (int q = 1; q < nc; q++) {
                float v = cv[q];
                if (fabsf(v) > fabsf(gval)) { gval = v; bk = __builtin_amdgcn_readfirstlane(ci[q]); }
            }
        }

        // ---- prefetch winner/guess codebook + Gram rows ----
        const float* cr = codebook + (size_t)bk * D_SZ + lane8;
        const _Float16* Gp = S + (size_t)(B_SZ + bk) * K_SZ + lane8;
        float4 c0 = *(const float4*)cr;
        float4 c1 = *(const float4*)(cr + 4);
        half8v Gh[8];
#pragma unroll
        for (int c = 0; c < 8; c++) Gh[c] = *(const half8v*)(Gp + c * 512);

        double bv, sd;
        if (fast) {
            if (M >= 4.0f) {
                // sign provably known from fp16 -> update proceeds; dot interleaves
                sd = ((gval >= 0.0f) ? 1.0 : -1.0) * decay;
                float sdf = (float)sd;
                h2 sdh2; sdh2[0] = (_Float16)sdf; sdh2[1] = (_Float16)sdf;
                upd(Gh, sdh2);
                bv = edot(c0, c1);
            } else {
                bv = edot(c0, c1);
                sd = ((bv >= 0.0) ? 1.0 : -1.0) * decay;
                float sdf = (float)sd;
                h2 sdh2; sdh2[0] = (_Float16)sdf; sdh2[1] = (_Float16)sdf;
                upd(Gh, sdh2);
            }
        } else {
            // exact rescore of every candidate
            int wk = -1; double wv = 0.0;
            for (int q = 0; q < nc; q++) {
                int k = __builtin_amdgcn_readfirstlane(ci[q]);
                const float* kr = codebook + (size_t)k * D_SZ + lane8;
                float4 d0 = *(const float4*)kr;
                float4 d1 = *(const float4*)(kr + 4);
                double s = edot(d0, d1);
                if (wk < 0 || fabs(s) > fabs(wv) ||
                    (fabs(s) == fabs(wv) && k < wk)) { wk = k; wv = s; }
            }
            if (wk != bk) {        // guess missed: reload winner rows
                bk = wk;
                const float* wr = codebook + (size_t)bk * D_SZ + lane8;
                const _Float16* Wp = S + (size_t)(B_SZ + bk) * K_SZ + lane8;
                c0 = *(const float4*)wr;
                c1 = *(const float4*)(wr + 4);
#pragma unroll
                for (int c = 0; c < 8; c++) Gh[c] = *(const half8v*)(Wp + c * 512);
            }
            bv = wv;
            sd = ((bv >= 0.0) ? 1.0 : -1.0) * decay;
            float sdf = (float)sd;
            h2 sdh2; sdh2[0] = (_Float16)sdf; sdh2[1] = (_Float16)sdf;
            upd(Gh, sdh2);
        }

        // ---- exact ||r||^2 identity + outputs ----
        const double cn2bk = cn2[bk];
        rn2 = rn2 - 2.0 * sd * bv + sd * sd * cn2bk;
        if (lane == 0) {
            __builtin_nontemporal_store((float)((bv >= 0.0) ? bk : (-bk - 1)), &out_seq[t]);
            __builtin_nontemporal_store(1.0f, &out_mask[t]);
        }

        // ---- exact diagonal patch (post-update; gmf/m stale-high by <=~0.3,
        //      covered by MARGIN, scan re-reads patched LDS) ----
        if (lane == 0) g[bk] = (_Float16)(float)(bv - sd * cn2bk);

        // ---- exact fp64 residual update (winner row in regs) ----
        rres[0] -= sd * (double)c0.x; rres[1] -= sd * (double)c0.y;
        rres[2] -= sd * (double)c0.z; rres[3] -= sd * (double)c0.w;
        rres[4] -= sd * (double)c1.x; rres[5] -= sd * (double)c1.y;
        rres[6] -= sd * (double)c1.z; rres[7] -= sd * (double)c1.w;
    }

    // ---- final residual (non-temporal) ----
    {
        f32x4 r0, r1;
        r0[0] = (float)rres[0]; r0[1] = (float)rres[1]; r0[2] = (float)rres[2]; r0[3] = (float)rres[3];
        r1[0] = (float)rres[4]; r1[1] = (float)rres[5]; r1[2] = (float)rres[6]; r1[3] = (float)rres[7];
        __builtin_nontemporal_store(r0, (f32x4*)(out_res + lane8));
        __builtin_nontemporal_store(r1, (f32x4*)(out_res + lane8 + 4));
    }
}

// ---------------------------------------------------------------------------
extern "C" void kernel_launch(void* const* d_in, const int* in_sizes, int n_in,
                              void* d_out, int out_size, void* d_ws, size_t ws_size,
                              hipStream_t stream) {
    const float* targets  = (const float*)d_in[0];
    const float* codebook = (const float*)d_in[1];
    float* out = (float*)d_out;

    __hip_bfloat16* abf = (__hip_bfloat16*)d_ws;                         // 12,582,912 B
    _Float16* S = (_Float16*)((char*)d_ws + (size_t)M_ALL * D_SZ * 2);   // 100,663,296 B
    double* cn2 = (double*)((char*)d_ws + (size_t)M_ALL * D_SZ * 2
                                        + (size_t)M_ALL * K_SZ * 2);     // 32,768 B
    // total ws needed: ~113.3 MB

    int total4 = (M_ALL * D_SZ) / 4;
    cast_bf16_kernel<<<(total4 + 255) / 256, 256, 0, stream>>>(targets, codebook, abf);
    cn2_kernel<<<K_SZ / 4, 256, 0, stream>>>(codebook, cn2);

    dim3 ggrid(K_SZ / BN, M_ALL / BM);
    gemm_bt_kernel<<<ggrid, 256, 0, stream>>>(abf, abf + (size_t)B_SZ * D_SZ, S);

    pursuit_kernel<<<B_SZ / 4, 256, 0, stream>>>(targets, codebook, S, cn2, out);
}